// Round 1
// baseline (1050.684 us; speedup 1.0000x reference)
//
#include <hip/hip_runtime.h>

// Phi3 quantized MLP on MI355X (gfx950).
// Pipeline: x->bf16 | dequant gup/down int4->bf16 | GEMM1 (gate+up fused, SiLU) | GEMM2 (+bias).
// GEMMs use the m97 structure: 128x128 tile, 4 waves, 16x16x32 bf16 MFMA,
// global_load_lds width=16 staging, 2-barrier K-loop.

typedef float  f32x4  __attribute__((ext_vector_type(4)));
typedef short  bf16x8 __attribute__((ext_vector_type(8)));

__device__ __forceinline__ unsigned short f2bf(float f) {
  unsigned int u = __float_as_uint(f);
  u += 0x7fffu + ((u >> 16) & 1u);       // RTNE
  return (unsigned short)(u >> 16);
}

__device__ __forceinline__ void gload16(const void* g, void* l) {
  __builtin_amdgcn_global_load_lds(
      (const __attribute__((address_space(1))) void*)g,
      (__attribute__((address_space(3))) void*)l, 16, 0, 0);
}

// ---------------- fp32 -> bf16 convert (x) ----------------
__global__ __launch_bounds__(256) void f32_to_bf16_k(const float* __restrict__ x,
                                                     unsigned short* __restrict__ y) {
  int idx = blockIdx.x * 256 + threadIdx.x;     // one thread = 8 elements
  const float4* x4 = (const float4*)x;
  float4 a = x4[idx * 2];
  float4 b = x4[idx * 2 + 1];
  uint4 o;
  o.x = f2bf(a.x) | ((unsigned)f2bf(a.y) << 16);
  o.y = f2bf(a.z) | ((unsigned)f2bf(a.w) << 16);
  o.z = f2bf(b.x) | ((unsigned)f2bf(b.y) << 16);
  o.w = f2bf(b.z) | ((unsigned)f2bf(b.w) << 16);
  ((uint4*)y)[idx] = o;
}

// ---------------- int4 group dequant -> bf16 ----------------
// qw: [rows, K] int32 (values 0..15), qz: [rows, K/128] int32, sc: [rows, K/128] f32
__global__ __launch_bounds__(256) void dequant_k(const int* __restrict__ qw,
                                                 const int* __restrict__ qz,
                                                 const float* __restrict__ sc,
                                                 unsigned short* __restrict__ W,
                                                 int K, int KG, int perrow /*K/8*/) {
  int idx = blockIdx.x * 256 + threadIdx.x;     // one thread = 8 elements of one row
  int row = idx / perrow;
  int c8  = idx - row * perrow;
  int k   = c8 << 3;
  int g   = k >> 7;                              // group size 128
  float z = (float)qz[row * KG + g];
  float s = sc[row * KG + g];
  float zs = -z * s;
  const int4* q4 = (const int4*)(qw + (size_t)row * K + k);
  int4 qa = q4[0];
  int4 qb = q4[1];
  uint4 o;
  o.x = f2bf(fmaf((float)qa.x, s, zs)) | ((unsigned)f2bf(fmaf((float)qa.y, s, zs)) << 16);
  o.y = f2bf(fmaf((float)qa.z, s, zs)) | ((unsigned)f2bf(fmaf((float)qa.w, s, zs)) << 16);
  o.z = f2bf(fmaf((float)qb.x, s, zs)) | ((unsigned)f2bf(fmaf((float)qb.y, s, zs)) << 16);
  o.w = f2bf(fmaf((float)qb.z, s, zs)) | ((unsigned)f2bf(fmaf((float)qb.w, s, zs)) << 16);
  *(uint4*)(W + (size_t)row * K + k) = o;
}

// ---------------- GEMM1: act = silu(x@Wg^T) * (x@Wu^T) ----------------
// Xb: [4096,3072] bf16, Wg: [16384,3072] bf16 (rows 0..8191 gate, 8192.. up),
// act: [4096,8192] bf16
__global__ __launch_bounds__(256, 2) void gemm_gateup(const unsigned short* __restrict__ Xb,
                                                      const unsigned short* __restrict__ Wg,
                                                      unsigned short* __restrict__ act) {
  const int K = 3072;
  const int n0 = blockIdx.x * 128;
  const int m0 = blockIdx.y * 128;
  __shared__ short lA[128 * 32];
  __shared__ short lG[128 * 32];
  __shared__ short lU[128 * 32];

  const int tid  = threadIdx.x;
  const int l    = tid & 63;
  const int w    = tid >> 6;
  const int quad = l >> 4;
  const int l16  = l & 15;
  const int wr   = (w >> 1) * 64;   // wave row base in tile
  const int wc   = (w & 1) * 64;    // wave col base in tile

  f32x4 cg[4][4] = {};
  f32x4 cu[4][4] = {};

  // staging: chunk c in [0,512): row=c>>2, 8-elem k-chunk=(c&3)
  const int c0 = tid, c1 = 256 + tid;
  const int r0 = c0 >> 2, kc0 = (c0 & 3) * 8;
  const int r1 = c1 >> 2, kc1 = (c1 & 3) * 8;
  const unsigned short* gA0 = Xb + (size_t)(m0 + r0) * K + kc0;
  const unsigned short* gA1 = Xb + (size_t)(m0 + r1) * K + kc1;
  const unsigned short* gG0 = Wg + (size_t)(n0 + r0) * K + kc0;
  const unsigned short* gG1 = Wg + (size_t)(n0 + r1) * K + kc1;
  const unsigned short* gU0 = Wg + (size_t)(8192 + n0 + r0) * K + kc0;
  const unsigned short* gU1 = Wg + (size_t)(8192 + n0 + r1) * K + kc1;

  for (int kk = 0; kk < K; kk += 32) {
    gload16(gA0 + kk, lA + c0 * 8);
    gload16(gA1 + kk, lA + c1 * 8);
    gload16(gG0 + kk, lG + c0 * 8);
    gload16(gG1 + kk, lG + c1 * 8);
    gload16(gU0 + kk, lU + c0 * 8);
    gload16(gU1 + kk, lU + c1 * 8);
    __syncthreads();   // compiler drains vmcnt(0) before s_barrier

    bf16x8 a[4];
#pragma unroll
    for (int i = 0; i < 4; ++i)
      a[i] = *(const bf16x8*)(lA + (wr + i * 16 + l16) * 32 + quad * 8);
#pragma unroll
    for (int j = 0; j < 4; ++j) {
      bf16x8 bg = *(const bf16x8*)(lG + (wc + j * 16 + l16) * 32 + quad * 8);
      bf16x8 bu = *(const bf16x8*)(lU + (wc + j * 16 + l16) * 32 + quad * 8);
#pragma unroll
      for (int i = 0; i < 4; ++i) {
        cg[i][j] = __builtin_amdgcn_mfma_f32_16x16x32_bf16(a[i], bg, cg[i][j], 0, 0, 0);
        cu[i][j] = __builtin_amdgcn_mfma_f32_16x16x32_bf16(a[i], bu, cu[i][j], 0, 0, 0);
      }
    }
    __syncthreads();
  }

  // epilogue: C/D layout col=lane&15, row=quad*4+reg
#pragma unroll
  for (int i = 0; i < 4; ++i)
#pragma unroll
    for (int j = 0; j < 4; ++j)
#pragma unroll
      for (int r = 0; r < 4; ++r) {
        int m = m0 + wr + i * 16 + quad * 4 + r;
        int n = n0 + wc + j * 16 + l16;
        float g = cg[i][j][r];
        float u = cu[i][j][r];
        float sg = g / (1.0f + __expf(-g));    // silu
        act[(size_t)m * 8192 + n] = f2bf(sg * u);
      }
}

// ---------------- GEMM2: out = act@Wd^T + bias ----------------
// A: [4096,8192] bf16, Wd: [3072,8192] bf16, out: [4096,3072] f32
__global__ __launch_bounds__(256, 2) void gemm_down(const unsigned short* __restrict__ A,
                                                    const unsigned short* __restrict__ Wd,
                                                    const float* __restrict__ bias,
                                                    float* __restrict__ out) {
  const int K = 8192;
  const int n0 = blockIdx.x * 128;
  const int m0 = blockIdx.y * 128;
  __shared__ short lA[128 * 32];
  __shared__ short lB[128 * 32];

  const int tid  = threadIdx.x;
  const int l    = tid & 63;
  const int w    = tid >> 6;
  const int quad = l >> 4;
  const int l16  = l & 15;
  const int wr   = (w >> 1) * 64;
  const int wc   = (w & 1) * 64;

  f32x4 c[4][4] = {};

  const int c0 = tid, c1 = 256 + tid;
  const int r0 = c0 >> 2, kc0 = (c0 & 3) * 8;
  const int r1 = c1 >> 2, kc1 = (c1 & 3) * 8;
  const unsigned short* gA0 = A + (size_t)(m0 + r0) * K + kc0;
  const unsigned short* gA1 = A + (size_t)(m0 + r1) * K + kc1;
  const unsigned short* gB0 = Wd + (size_t)(n0 + r0) * K + kc0;
  const unsigned short* gB1 = Wd + (size_t)(n0 + r1) * K + kc1;

  for (int kk = 0; kk < K; kk += 32) {
    gload16(gA0 + kk, lA + c0 * 8);
    gload16(gA1 + kk, lA + c1 * 8);
    gload16(gB0 + kk, lB + c0 * 8);
    gload16(gB1 + kk, lB + c1 * 8);
    __syncthreads();

    bf16x8 a[4];
#pragma unroll
    for (int i = 0; i < 4; ++i)
      a[i] = *(const bf16x8*)(lA + (wr + i * 16 + l16) * 32 + quad * 8);
#pragma unroll
    for (int j = 0; j < 4; ++j) {
      bf16x8 b = *(const bf16x8*)(lB + (wc + j * 16 + l16) * 32 + quad * 8);
#pragma unroll
      for (int i = 0; i < 4; ++i)
        c[i][j] = __builtin_amdgcn_mfma_f32_16x16x32_bf16(a[i], b, c[i][j], 0, 0, 0);
    }
    __syncthreads();
  }

  float bj[4];
#pragma unroll
  for (int j = 0; j < 4; ++j) bj[j] = bias[n0 + wc + j * 16 + l16];

#pragma unroll
  for (int i = 0; i < 4; ++i)
#pragma unroll
    for (int j = 0; j < 4; ++j)
#pragma unroll
      for (int r = 0; r < 4; ++r) {
        int m = m0 + wr + i * 16 + quad * 4 + r;
        int n = n0 + wc + j * 16 + l16;
        out[(size_t)m * 3072 + n] = c[i][j][r] + bj[j];
      }
}

extern "C" void kernel_launch(void* const* d_in, const int* in_sizes, int n_in,
                              void* d_out, int out_size, void* d_ws, size_t ws_size,
                              hipStream_t stream) {
  const float* x        = (const float*)d_in[0];
  const int*   gup_qw   = (const int*)d_in[1];
  const int*   gup_qz   = (const int*)d_in[2];
  const float* gup_sc   = (const float*)d_in[3];
  const int*   down_qw  = (const int*)d_in[4];
  const int*   down_qz  = (const int*)d_in[5];
  const float* down_sc  = (const float*)d_in[6];
  const float* down_b   = (const float*)d_in[7];
  float* out = (float*)d_out;

  // ws layout (bytes): Xb 25,165,824 | Wgup 100,663,296 | Wdown 50,331,648 | Act 67,108,864
  char* ws = (char*)d_ws;
  unsigned short* Xb    = (unsigned short*)(ws);
  unsigned short* Wgup  = (unsigned short*)(ws + 25165824);
  unsigned short* Wdown = (unsigned short*)(ws + 125829120);
  unsigned short* Act   = (unsigned short*)(ws + 176160768);

  // x: 4096*3072 = 12,582,912 elems -> /8 = 1,572,864 threads
  f32_to_bf16_k<<<6144, 256, 0, stream>>>(x, Xb);
  // gup: 16384 rows * 3072 -> 6,291,456 threads of 8
  dequant_k<<<24576, 256, 0, stream>>>(gup_qw, gup_qz, gup_sc, Wgup, 3072, 24, 384);
  // down: 3072 rows * 8192 -> 3,145,728 threads of 8
  dequant_k<<<12288, 256, 0, stream>>>(down_qw, down_qz, down_sc, Wdown, 8192, 64, 1024);
  // GEMM1: M=4096, N(gate)=8192 -> grid (64, 32)
  gemm_gateup<<<dim3(64, 32), 256, 0, stream>>>(Xb, Wgup, Act);
  // GEMM2: M=4096, N=3072 -> grid (24, 32)
  gemm_down<<<dim3(24, 32), 256, 0, stream>>>(Act, Wdown, down_b, out);
}

// Round 2
// 973.550 us; speedup vs baseline: 1.0792x; 1.0792x over previous
//
#include <hip/hip_runtime.h>

// Phi3 quantized MLP on MI355X (gfx950).
// R2: BK=64 K-loop (halved barrier count) + XOR-swizzled LDS (kills the 8-way
// bank conflicts seen in R1: SQ_LDS_BANK_CONFLICT 3.78e7/dispatch).
// Swizzle: LDS slot for (row, kchunk) holds kchunk ^ (row&7); global_load_lds
// keeps its forced base+lane*16 LDS placement, the *global* address is permuted.

typedef float  f32x4  __attribute__((ext_vector_type(4)));
typedef short  bf16x8 __attribute__((ext_vector_type(8)));

__device__ __forceinline__ unsigned short f2bf(float f) {
  unsigned int u = __float_as_uint(f);
  u += 0x7fffu + ((u >> 16) & 1u);       // RTNE
  return (unsigned short)(u >> 16);
}

__device__ __forceinline__ void gload16(const void* g, void* l) {
  __builtin_amdgcn_global_load_lds(
      (const __attribute__((address_space(1))) void*)g,
      (__attribute__((address_space(3))) void*)l, 16, 0, 0);
}

// ---------------- fp32 -> bf16 convert (x) ----------------
__global__ __launch_bounds__(256) void f32_to_bf16_k(const float* __restrict__ x,
                                                     unsigned short* __restrict__ y) {
  int idx = blockIdx.x * 256 + threadIdx.x;     // one thread = 8 elements
  const float4* x4 = (const float4*)x;
  float4 a = x4[idx * 2];
  float4 b = x4[idx * 2 + 1];
  uint4 o;
  o.x = f2bf(a.x) | ((unsigned)f2bf(a.y) << 16);
  o.y = f2bf(a.z) | ((unsigned)f2bf(a.w) << 16);
  o.z = f2bf(b.x) | ((unsigned)f2bf(b.y) << 16);
  o.w = f2bf(b.z) | ((unsigned)f2bf(b.w) << 16);
  ((uint4*)y)[idx] = o;
}

// ---------------- int4 group dequant -> bf16 ----------------
// qw: [rows, K] int32 (0..15), qz: [rows, K/128] int32, sc: [rows, K/128] f32
template <int K>
__global__ __launch_bounds__(256) void dequant_k(const int* __restrict__ qw,
                                                 const int* __restrict__ qz,
                                                 const float* __restrict__ sc,
                                                 unsigned short* __restrict__ W) {
  constexpr int KG = K / 128;
  constexpr int perrow = K / 8;
  int idx = blockIdx.x * 256 + threadIdx.x;     // one thread = 8 elements of one row
  int row = idx / perrow;                       // div by constant -> magic mul
  int c8  = idx - row * perrow;
  int k   = c8 << 3;
  int g   = k >> 7;
  float z = (float)qz[row * KG + g];
  float s = sc[row * KG + g];
  float zs = -z * s;
  const int4* q4 = (const int4*)(qw + (size_t)row * K + k);
  int4 qa = q4[0];
  int4 qb = q4[1];
  uint4 o;
  o.x = f2bf(fmaf((float)qa.x, s, zs)) | ((unsigned)f2bf(fmaf((float)qa.y, s, zs)) << 16);
  o.y = f2bf(fmaf((float)qa.z, s, zs)) | ((unsigned)f2bf(fmaf((float)qa.w, s, zs)) << 16);
  o.z = f2bf(fmaf((float)qb.x, s, zs)) | ((unsigned)f2bf(fmaf((float)qb.y, s, zs)) << 16);
  o.w = f2bf(fmaf((float)qb.z, s, zs)) | ((unsigned)f2bf(fmaf((float)qb.w, s, zs)) << 16);
  *(uint4*)(W + (size_t)row * K + k) = o;
}

// LDS tile: 128 rows x 64 halfs (row stride 128B). Slot = 16B chunk.
// (row, physical slot p) holds logical k-chunk (p ^ (row&7)).
// Fragment read addr (shorts): row*64 + ((slot ^ (row&7)) * 8).

// ---------------- GEMM1: act = silu(x@Wg^T) * (x@Wu^T) ----------------
__global__ __launch_bounds__(256, 2) void gemm_gateup(const unsigned short* __restrict__ Xb,
                                                      const unsigned short* __restrict__ Wg,
                                                      unsigned short* __restrict__ act) {
  const int K = 3072;
  const int n0 = blockIdx.x * 128;
  const int m0 = blockIdx.y * 128;
  __shared__ short lA[128 * 64];
  __shared__ short lG[128 * 64];
  __shared__ short lU[128 * 64];

  const int tid  = threadIdx.x;
  const int l    = tid & 63;
  const int quad = l >> 4;
  const int l16  = l & 15;
  const int wr   = ((tid >> 6) >> 1) * 64;   // wave row base
  const int wc   = ((tid >> 6) & 1) * 64;    // wave col base

  f32x4 cg[4][4] = {};
  f32x4 cu[4][4] = {};

  // staging: 1024 chunks/tile, 4 per thread. chunk c: row=c>>3, phys=c&7,
  // logical kchunk = phys ^ (row&7). Same (row, offset) for all three tiles.
  int off[4];
#pragma unroll
  for (int j = 0; j < 4; ++j) {
    int c   = tid + 256 * j;
    int row = c >> 3;
    int log = (c & 7) ^ (row & 7);
    off[j]  = row * K + log * 8;
  }
  const unsigned short* baseA = Xb + (size_t)m0 * K;
  const unsigned short* baseG = Wg + (size_t)n0 * K;
  const unsigned short* baseU = Wg + (size_t)(8192 + n0) * K;

  // fragment LDS offsets (shorts), swizzled
  int aoff[2][4], boff[2][4];
#pragma unroll
  for (int h = 0; h < 2; ++h) {
    int slot = h * 4 + quad;
#pragma unroll
    for (int i = 0; i < 4; ++i) {
      int ra = wr + i * 16 + l16;
      aoff[h][i] = ra * 64 + ((slot ^ (ra & 7)) * 8);
      int rb = wc + i * 16 + l16;
      boff[h][i] = rb * 64 + ((slot ^ (rb & 7)) * 8);
    }
  }

  for (int kk = 0; kk < K; kk += 64) {
#pragma unroll
    for (int j = 0; j < 4; ++j) {
      gload16(baseA + off[j] + kk, lA + (tid + 256 * j) * 8);
      gload16(baseG + off[j] + kk, lG + (tid + 256 * j) * 8);
      gload16(baseU + off[j] + kk, lU + (tid + 256 * j) * 8);
    }
    __syncthreads();

#pragma unroll
    for (int h = 0; h < 2; ++h) {
      bf16x8 a[4];
#pragma unroll
      for (int i = 0; i < 4; ++i) a[i] = *(const bf16x8*)(lA + aoff[h][i]);
#pragma unroll
      for (int j = 0; j < 4; ++j) {
        bf16x8 bg = *(const bf16x8*)(lG + boff[h][j]);
        bf16x8 bu = *(const bf16x8*)(lU + boff[h][j]);
#pragma unroll
        for (int i = 0; i < 4; ++i) {
          cg[i][j] = __builtin_amdgcn_mfma_f32_16x16x32_bf16(a[i], bg, cg[i][j], 0, 0, 0);
          cu[i][j] = __builtin_amdgcn_mfma_f32_16x16x32_bf16(a[i], bu, cu[i][j], 0, 0, 0);
        }
      }
    }
    __syncthreads();
  }

  // epilogue: C/D layout col=lane&15, row=quad*4+reg
#pragma unroll
  for (int i = 0; i < 4; ++i)
#pragma unroll
    for (int j = 0; j < 4; ++j)
#pragma unroll
      for (int r = 0; r < 4; ++r) {
        int m = m0 + wr + i * 16 + quad * 4 + r;
        int n = n0 + wc + j * 16 + l16;
        float g = cg[i][j][r];
        float u = cu[i][j][r];
        float sg = g / (1.0f + __expf(-g));    // silu
        act[(size_t)m * 8192 + n] = f2bf(sg * u);
      }
}

// ---------------- GEMM2: out = act@Wd^T + bias ----------------
__global__ __launch_bounds__(256, 2) void gemm_down(const unsigned short* __restrict__ A,
                                                    const unsigned short* __restrict__ Wd,
                                                    const float* __restrict__ bias,
                                                    float* __restrict__ out) {
  const int K = 8192;
  const int n0 = blockIdx.x * 128;
  const int m0 = blockIdx.y * 128;
  __shared__ short lA[128 * 64];
  __shared__ short lB[128 * 64];

  const int tid  = threadIdx.x;
  const int l    = tid & 63;
  const int quad = l >> 4;
  const int l16  = l & 15;
  const int wr   = ((tid >> 6) >> 1) * 64;
  const int wc   = ((tid >> 6) & 1) * 64;

  f32x4 c[4][4] = {};

  int off[4];
#pragma unroll
  for (int j = 0; j < 4; ++j) {
    int cc  = tid + 256 * j;
    int row = cc >> 3;
    int log = (cc & 7) ^ (row & 7);
    off[j]  = row * K + log * 8;
  }
  const unsigned short* baseA = A  + (size_t)m0 * K;
  const unsigned short* baseB = Wd + (size_t)n0 * K;

  int aoff[2][4], boff[2][4];
#pragma unroll
  for (int h = 0; h < 2; ++h) {
    int slot = h * 4 + quad;
#pragma unroll
    for (int i = 0; i < 4; ++i) {
      int ra = wr + i * 16 + l16;
      aoff[h][i] = ra * 64 + ((slot ^ (ra & 7)) * 8);
      int rb = wc + i * 16 + l16;
      boff[h][i] = rb * 64 + ((slot ^ (rb & 7)) * 8);
    }
  }

  for (int kk = 0; kk < K; kk += 64) {
#pragma unroll
    for (int j = 0; j < 4; ++j) {
      gload16(baseA + off[j] + kk, lA + (tid + 256 * j) * 8);
      gload16(baseB + off[j] + kk, lB + (tid + 256 * j) * 8);
    }
    __syncthreads();

#pragma unroll
    for (int h = 0; h < 2; ++h) {
      bf16x8 a[4];
#pragma unroll
      for (int i = 0; i < 4; ++i) a[i] = *(const bf16x8*)(lA + aoff[h][i]);
#pragma unroll
      for (int j = 0; j < 4; ++j) {
        bf16x8 b = *(const bf16x8*)(lB + boff[h][j]);
#pragma unroll
        for (int i = 0; i < 4; ++i)
          c[i][j] = __builtin_amdgcn_mfma_f32_16x16x32_bf16(a[i], b, c[i][j], 0, 0, 0);
      }
    }
    __syncthreads();
  }

  float bj[4];
#pragma unroll
  for (int j = 0; j < 4; ++j) bj[j] = bias[n0 + wc + j * 16 + l16];

#pragma unroll
  for (int i = 0; i < 4; ++i)
#pragma unroll
    for (int j = 0; j < 4; ++j)
#pragma unroll
      for (int r = 0; r < 4; ++r) {
        int m = m0 + wr + i * 16 + quad * 4 + r;
        int n = n0 + wc + j * 16 + l16;
        out[(size_t)m * 3072 + n] = c[i][j][r] + bj[j];
      }
}

extern "C" void kernel_launch(void* const* d_in, const int* in_sizes, int n_in,
                              void* d_out, int out_size, void* d_ws, size_t ws_size,
                              hipStream_t stream) {
  const float* x        = (const float*)d_in[0];
  const int*   gup_qw   = (const int*)d_in[1];
  const int*   gup_qz   = (const int*)d_in[2];
  const float* gup_sc   = (const float*)d_in[3];
  const int*   down_qw  = (const int*)d_in[4];
  const int*   down_qz  = (const int*)d_in[5];
  const float* down_sc  = (const float*)d_in[6];
  const float* down_b   = (const float*)d_in[7];
  float* out = (float*)d_out;

  // ws layout (bytes): Xb 25,165,824 | Wgup 100,663,296 | Wdown 50,331,648 | Act 67,108,864
  char* ws = (char*)d_ws;
  unsigned short* Xb    = (unsigned short*)(ws);
  unsigned short* Wgup  = (unsigned short*)(ws + 25165824);
  unsigned short* Wdown = (unsigned short*)(ws + 125829120);
  unsigned short* Act   = (unsigned short*)(ws + 176160768);

  f32_to_bf16_k<<<6144, 256, 0, stream>>>(x, Xb);
  dequant_k<3072><<<24576, 256, 0, stream>>>(gup_qw, gup_qz, gup_sc, Wgup);
  dequant_k<8192><<<12288, 256, 0, stream>>>(down_qw, down_qz, down_sc, Wdown);
  gemm_gateup<<<dim3(64, 32), 256, 0, stream>>>(Xb, Wgup, Act);
  gemm_down<<<dim3(24, 32), 256, 0, stream>>>(Act, Wdown, down_b, out);
}

// Round 3
// 949.968 us; speedup vs baseline: 1.1060x; 1.0248x over previous
//
#include <hip/hip_runtime.h>

// Phi3 quantized MLP on MI355X (gfx950).
// R3: XCD-aware block clustering. R2 analysis: staged LDS traffic (4.6 GB gateup,
// 3.2 GB down) at measured 11.5 TB/s == Infinity-Cache ceiling; intensity (85 /
// 64 FLOP per staged byte) x 11.5 TB/s exactly predicts both kernels' TF.
// Remap blockIdx so each XCD's ~64 co-resident blocks form a compact 2D tile
// region streaming K in lockstep -> per-K-step chunks fit the 4 MB per-XCD L2.

typedef float  f32x4  __attribute__((ext_vector_type(4)));
typedef short  bf16x8 __attribute__((ext_vector_type(8)));

__device__ __forceinline__ unsigned short f2bf(float f) {
  unsigned int u = __float_as_uint(f);
  u += 0x7fffu + ((u >> 16) & 1u);       // RTNE
  return (unsigned short)(u >> 16);
}

__device__ __forceinline__ void gload16(const void* g, void* l) {
  __builtin_amdgcn_global_load_lds(
      (const __attribute__((address_space(1))) void*)g,
      (__attribute__((address_space(3))) void*)l, 16, 0, 0);
}

// ---------------- fp32 -> bf16 convert (x) ----------------
__global__ __launch_bounds__(256) void f32_to_bf16_k(const float* __restrict__ x,
                                                     unsigned short* __restrict__ y) {
  int idx = blockIdx.x * 256 + threadIdx.x;     // one thread = 8 elements
  const float4* x4 = (const float4*)x;
  float4 a = x4[idx * 2];
  float4 b = x4[idx * 2 + 1];
  uint4 o;
  o.x = f2bf(a.x) | ((unsigned)f2bf(a.y) << 16);
  o.y = f2bf(a.z) | ((unsigned)f2bf(a.w) << 16);
  o.z = f2bf(b.x) | ((unsigned)f2bf(b.y) << 16);
  o.w = f2bf(b.z) | ((unsigned)f2bf(b.w) << 16);
  ((uint4*)y)[idx] = o;
}

// ---------------- int4 group dequant -> bf16 ----------------
template <int K>
__global__ __launch_bounds__(256) void dequant_k(const int* __restrict__ qw,
                                                 const int* __restrict__ qz,
                                                 const float* __restrict__ sc,
                                                 unsigned short* __restrict__ W) {
  constexpr int KG = K / 128;
  constexpr int perrow = K / 8;
  int idx = blockIdx.x * 256 + threadIdx.x;     // one thread = 8 elements of one row
  int row = idx / perrow;
  int c8  = idx - row * perrow;
  int k   = c8 << 3;
  int g   = k >> 7;
  float z = (float)qz[row * KG + g];
  float s = sc[row * KG + g];
  float zs = -z * s;
  const int4* q4 = (const int4*)(qw + (size_t)row * K + k);
  int4 qa = q4[0];
  int4 qb = q4[1];
  uint4 o;
  o.x = f2bf(fmaf((float)qa.x, s, zs)) | ((unsigned)f2bf(fmaf((float)qa.y, s, zs)) << 16);
  o.y = f2bf(fmaf((float)qa.z, s, zs)) | ((unsigned)f2bf(fmaf((float)qa.w, s, zs)) << 16);
  o.z = f2bf(fmaf((float)qb.x, s, zs)) | ((unsigned)f2bf(fmaf((float)qb.y, s, zs)) << 16);
  o.w = f2bf(fmaf((float)qb.z, s, zs)) | ((unsigned)f2bf(fmaf((float)qb.w, s, zs)) << 16);
  *(uint4*)(W + (size_t)row * K + k) = o;
}

// LDS tile: 128 rows x 64 halfs. XOR swizzle: (row, phys slot p) holds chunk p^(row&7).

// ---------------- GEMM1: act = silu(x@Wg^T) * (x@Wu^T) ----------------
// grid: 2048 1D. XCD x <- n-band {8x..8x+7}, m-major inside -> resident 8n x 8m.
__global__ __launch_bounds__(256, 2) void gemm_gateup(const unsigned short* __restrict__ Xb,
                                                      const unsigned short* __restrict__ Wg,
                                                      unsigned short* __restrict__ act) {
  const int K = 3072;
  const int bid = blockIdx.x;
  const int xcd = bid & 7;
  const int j   = bid >> 3;              // 0..255
  const int n0  = ((xcd << 3) + (j & 7)) * 128;   // n-tile 0..63
  const int m0  = (j >> 3) * 128;                 // m-tile 0..31
  __shared__ short lA[128 * 64];
  __shared__ short lG[128 * 64];
  __shared__ short lU[128 * 64];

  const int tid  = threadIdx.x;
  const int l    = tid & 63;
  const int quad = l >> 4;
  const int l16  = l & 15;
  const int wr   = ((tid >> 6) >> 1) * 64;
  const int wc   = ((tid >> 6) & 1) * 64;

  f32x4 cg[4][4] = {};
  f32x4 cu[4][4] = {};

  int off[4];
#pragma unroll
  for (int jj = 0; jj < 4; ++jj) {
    int c   = tid + 256 * jj;
    int row = c >> 3;
    int log = (c & 7) ^ (row & 7);
    off[jj] = row * K + log * 8;
  }
  const unsigned short* baseA = Xb + (size_t)m0 * K;
  const unsigned short* baseG = Wg + (size_t)n0 * K;
  const unsigned short* baseU = Wg + (size_t)(8192 + n0) * K;

  int aoff[2][4], boff[2][4];
#pragma unroll
  for (int h = 0; h < 2; ++h) {
    int slot = h * 4 + quad;
#pragma unroll
    for (int i = 0; i < 4; ++i) {
      int ra = wr + i * 16 + l16;
      aoff[h][i] = ra * 64 + ((slot ^ (ra & 7)) * 8);
      int rb = wc + i * 16 + l16;
      boff[h][i] = rb * 64 + ((slot ^ (rb & 7)) * 8);
    }
  }

  for (int kk = 0; kk < K; kk += 64) {
#pragma unroll
    for (int jj = 0; jj < 4; ++jj) {
      gload16(baseA + off[jj] + kk, lA + (tid + 256 * jj) * 8);
      gload16(baseG + off[jj] + kk, lG + (tid + 256 * jj) * 8);
      gload16(baseU + off[jj] + kk, lU + (tid + 256 * jj) * 8);
    }
    __syncthreads();

#pragma unroll
    for (int h = 0; h < 2; ++h) {
      bf16x8 a[4];
#pragma unroll
      for (int i = 0; i < 4; ++i) a[i] = *(const bf16x8*)(lA + aoff[h][i]);
#pragma unroll
      for (int jj = 0; jj < 4; ++jj) {
        bf16x8 bg = *(const bf16x8*)(lG + boff[h][jj]);
        bf16x8 bu = *(const bf16x8*)(lU + boff[h][jj]);
#pragma unroll
        for (int i = 0; i < 4; ++i) {
          cg[i][jj] = __builtin_amdgcn_mfma_f32_16x16x32_bf16(a[i], bg, cg[i][jj], 0, 0, 0);
          cu[i][jj] = __builtin_amdgcn_mfma_f32_16x16x32_bf16(a[i], bu, cu[i][jj], 0, 0, 0);
        }
      }
    }
    __syncthreads();
  }

#pragma unroll
  for (int i = 0; i < 4; ++i)
#pragma unroll
    for (int jj = 0; jj < 4; ++jj)
#pragma unroll
      for (int r = 0; r < 4; ++r) {
        int m = m0 + wr + i * 16 + quad * 4 + r;
        int n = n0 + wc + jj * 16 + l16;
        float g = cg[i][jj][r];
        float u = cu[i][jj][r];
        float sg = g / (1.0f + __expf(-g));    // silu
        act[(size_t)m * 8192 + n] = f2bf(sg * u);
      }
}

// ---------------- GEMM2: out = act@Wd^T + bias ----------------
// grid: 768 1D. XCD x <- exact (12n x 8m) region (2x4 regions), n-major inside.
__global__ __launch_bounds__(256, 2) void gemm_down(const unsigned short* __restrict__ A,
                                                    const unsigned short* __restrict__ Wd,
                                                    const float* __restrict__ bias,
                                                    float* __restrict__ out) {
  const int K = 8192;
  const int bid = blockIdx.x;
  const int xcd = bid & 7;
  const int j   = bid >> 3;              // 0..95
  const int jn  = j % 12;
  const int jm  = j / 12;
  const int n0  = (12 * (xcd & 1) + jn) * 128;   // n-tile 0..23
  const int m0  = (8 * (xcd >> 1) + jm) * 128;   // m-tile 0..31
  __shared__ short lA[128 * 64];
  __shared__ short lB[128 * 64];

  const int tid  = threadIdx.x;
  const int l    = tid & 63;
  const int quad = l >> 4;
  const int l16  = l & 15;
  const int wr   = ((tid >> 6) >> 1) * 64;
  const int wc   = ((tid >> 6) & 1) * 64;

  f32x4 c[4][4] = {};

  int off[4];
#pragma unroll
  for (int jj = 0; jj < 4; ++jj) {
    int cc  = tid + 256 * jj;
    int row = cc >> 3;
    int log = (cc & 7) ^ (row & 7);
    off[jj] = row * K + log * 8;
  }
  const unsigned short* baseA = A  + (size_t)m0 * K;
  const unsigned short* baseB = Wd + (size_t)n0 * K;

  int aoff[2][4], boff[2][4];
#pragma unroll
  for (int h = 0; h < 2; ++h) {
    int slot = h * 4 + quad;
#pragma unroll
    for (int i = 0; i < 4; ++i) {
      int ra = wr + i * 16 + l16;
      aoff[h][i] = ra * 64 + ((slot ^ (ra & 7)) * 8);
      int rb = wc + i * 16 + l16;
      boff[h][i] = rb * 64 + ((slot ^ (rb & 7)) * 8);
    }
  }

  for (int kk = 0; kk < K; kk += 64) {
#pragma unroll
    for (int jj = 0; jj < 4; ++jj) {
      gload16(baseA + off[jj] + kk, lA + (tid + 256 * jj) * 8);
      gload16(baseB + off[jj] + kk, lB + (tid + 256 * jj) * 8);
    }
    __syncthreads();

#pragma unroll
    for (int h = 0; h < 2; ++h) {
      bf16x8 a[4];
#pragma unroll
      for (int i = 0; i < 4; ++i) a[i] = *(const bf16x8*)(lA + aoff[h][i]);
#pragma unroll
      for (int jj = 0; jj < 4; ++jj) {
        bf16x8 b = *(const bf16x8*)(lB + boff[h][jj]);
#pragma unroll
        for (int i = 0; i < 4; ++i)
          c[i][jj] = __builtin_amdgcn_mfma_f32_16x16x32_bf16(a[i], b, c[i][jj], 0, 0, 0);
      }
    }
    __syncthreads();
  }

  float bj[4];
#pragma unroll
  for (int jj = 0; jj < 4; ++jj) bj[jj] = bias[n0 + wc + jj * 16 + l16];

#pragma unroll
  for (int i = 0; i < 4; ++i)
#pragma unroll
    for (int jj = 0; jj < 4; ++jj)
#pragma unroll
      for (int r = 0; r < 4; ++r) {
        int m = m0 + wr + i * 16 + quad * 4 + r;
        int n = n0 + wc + jj * 16 + l16;
        out[(size_t)m * 3072 + n] = c[i][jj][r] + bj[jj];
      }
}

extern "C" void kernel_launch(void* const* d_in, const int* in_sizes, int n_in,
                              void* d_out, int out_size, void* d_ws, size_t ws_size,
                              hipStream_t stream) {
  const float* x        = (const float*)d_in[0];
  const int*   gup_qw   = (const int*)d_in[1];
  const int*   gup_qz   = (const int*)d_in[2];
  const float* gup_sc   = (const float*)d_in[3];
  const int*   down_qw  = (const int*)d_in[4];
  const int*   down_qz  = (const int*)d_in[5];
  const float* down_sc  = (const float*)d_in[6];
  const float* down_b   = (const float*)d_in[7];
  float* out = (float*)d_out;

  // ws layout (bytes): Xb 25,165,824 | Wgup 100,663,296 | Wdown 50,331,648 | Act 67,108,864
  char* ws = (char*)d_ws;
  unsigned short* Xb    = (unsigned short*)(ws);
  unsigned short* Wgup  = (unsigned short*)(ws + 25165824);
  unsigned short* Wdown = (unsigned short*)(ws + 125829120);
  unsigned short* Act   = (unsigned short*)(ws + 176160768);

  f32_to_bf16_k<<<6144, 256, 0, stream>>>(x, Xb);
  dequant_k<3072><<<24576, 256, 0, stream>>>(gup_qw, gup_qz, gup_sc, Wgup);
  dequant_k<8192><<<12288, 256, 0, stream>>>(down_qw, down_qz, down_sc, Wdown);
  gemm_gateup<<<2048, 256, 0, stream>>>(Xb, Wgup, Act);
  gemm_down<<<768, 256, 0, stream>>>(Act, Wdown, down_b, out);
}

// Round 4
// 837.350 us; speedup vs baseline: 1.2548x; 1.1345x over previous
//
#include <hip/hip_runtime.h>

// Phi3 quantized MLP on MI355X (gfx950) — R4: int8 MFMA path.
// R3 post-mortem: LDS port is the wall (143 B/cyc/CU vs ~112 ceiling).
// int8 halves LDS bytes AND doubles MFMA rate. Weights (q-z) in [-15,15] are
// EXACT in int8; x/act quantized symmetric per K-group of 128 (the quant
// group), rescaled into f32 accumulators every group via per-group scales.

typedef float f32x4 __attribute__((ext_vector_type(4)));
typedef int   i32x4 __attribute__((ext_vector_type(4)));

__device__ __forceinline__ void gload16(const void* g, void* l) {
  __builtin_amdgcn_global_load_lds(
      (const __attribute__((address_space(1))) void*)g,
      (__attribute__((address_space(3))) void*)l, 16, 0, 0);
}

// ---------------- quantize x: f32 -> int8 per (row, group of 128) ----------------
// XsT: [24][4096] transposed scales
__global__ __launch_bounds__(256) void quant_x(const float* __restrict__ x,
                                               signed char* __restrict__ Xq,
                                               float* __restrict__ XsT) {
  int gidx = blockIdx.x * 4 + (threadIdx.x >> 6);   // group index 0..98303
  int lane = threadIdx.x & 63;
  int row = gidx / 24;
  int g   = gidx - row * 24;
  const float2 v = *(const float2*)(x + (size_t)row * 3072 + g * 128 + lane * 2);
  float m = fmaxf(fabsf(v.x), fabsf(v.y));
#pragma unroll
  for (int s = 1; s < 64; s <<= 1) m = fmaxf(m, __shfl_xor(m, s));
  float inv = m > 0.f ? 127.f / m : 0.f;
  int qa = (int)rintf(v.x * inv);
  int qb = (int)rintf(v.y * inv);
  unsigned short pk = (unsigned short)((qa & 0xff) | ((qb & 0xff) << 8));
  *(unsigned short*)(Xq + (size_t)row * 3072 + g * 128 + lane * 2) = pk;
  if (lane == 0) XsT[g * 4096 + row] = m * (1.f / 127.f);
}

// ---------------- requant weights: int32 q,z -> int8 (q - z) ----------------
template <int K>
__global__ __launch_bounds__(256) void requant_k(const int* __restrict__ qw,
                                                 const int* __restrict__ qz,
                                                 signed char* __restrict__ W) {
  constexpr int KG = K / 128;
  constexpr int perrow = K / 8;
  int idx = blockIdx.x * 256 + threadIdx.x;
  int row = idx / perrow;
  int c8  = idx - row * perrow;
  int k   = c8 << 3;
  int z   = qz[row * KG + (k >> 7)];
  const int4* q4 = (const int4*)(qw + (size_t)row * K + k);
  int4 qa = q4[0];
  int4 qb = q4[1];
  int b0 = ((qa.x - z) & 0xff) | (((qa.y - z) & 0xff) << 8) |
           (((qa.z - z) & 0xff) << 16) | (((qa.w - z) & 0xff) << 24);
  int b1 = ((qb.x - z) & 0xff) | (((qb.y - z) & 0xff) << 8) |
           (((qb.z - z) & 0xff) << 16) | (((qb.w - z) & 0xff) << 24);
  int2 o; o.x = b0; o.y = b1;
  *(int2*)(W + (size_t)row * K + k) = o;
}

// ---------------- scale transpose: [R][G] -> [G][R] ----------------
__global__ __launch_bounds__(256) void transpose_sc(const float* __restrict__ in,
                                                    float* __restrict__ out,
                                                    int R, int G) {
  int idx = blockIdx.x * 256 + threadIdx.x;
  int r = idx / G;
  int g = idx - r * G;
  out[(size_t)g * R + r] = in[idx];
}

// LDS tile: 128 rows x 128 bytes (8 chunks of 16B). XOR swizzle: phys chunk p of
// row holds logical chunk p^(row&7). Fragment read (K64-half h): chunk h*4+quad.

// ---------------- GEMM1: act = silu(x@Wg^T)*(x@Wu^T), int8 in, int8 out ----------------
__global__ __launch_bounds__(256, 2) void gemm_gateup_i8(
    const signed char* __restrict__ Xq, const signed char* __restrict__ Wq,
    const float* __restrict__ XsT,   // [24][4096]
    const float* __restrict__ GsT,   // [24][16384]
    signed char* __restrict__ act,   // [4096][8192]
    float* __restrict__ AsT) {       // [64][4096]
  const int K = 3072;
  const int bid = blockIdx.x;
  const int xcd = bid & 7;
  const int jb  = bid >> 3;
  const int n0  = ((xcd << 3) + (jb & 7)) * 128;
  const int m0  = (jb >> 3) * 128;
  __shared__ signed char lA[16384];
  __shared__ signed char lG[16384];
  __shared__ signed char lU[16384];
  __shared__ float rmax[2][128];

  const int tid  = threadIdx.x;
  const int l    = tid & 63;
  const int quad = l >> 4;
  const int l16  = l & 15;
  const int wcI  = (tid >> 6) & 1;
  const int wr   = ((tid >> 6) >> 1) * 64;
  const int wc   = wcI * 64;

  f32x4 fg[4][4] = {};
  f32x4 fu[4][4] = {};

  int off[4];
#pragma unroll
  for (int jj = 0; jj < 4; ++jj) {
    int c   = tid + 256 * jj;
    int row = c >> 3;
    int log = (c & 7) ^ (row & 7);
    off[jj] = row * K + log * 16;
  }
  const signed char* baseA = Xq + (size_t)m0 * K;
  const signed char* baseG = Wq + (size_t)n0 * K;
  const signed char* baseU = Wq + (size_t)(8192 + n0) * K;

  int aoff[2][4], boff[2][4];
#pragma unroll
  for (int h = 0; h < 2; ++h) {
    int slot = h * 4 + quad;
#pragma unroll
    for (int i = 0; i < 4; ++i) {
      int ra = wr + i * 16 + l16;
      aoff[h][i] = ra * 128 + ((slot ^ (ra & 7)) * 16);
      int rb = wc + i * 16 + l16;
      boff[h][i] = rb * 128 + ((slot ^ (rb & 7)) * 16);
    }
  }

  for (int g = 0; g < 24; ++g) {
    const int kk = g << 7;
#pragma unroll
    for (int jj = 0; jj < 4; ++jj) {
      gload16(baseA + off[jj] + kk, lA + (tid + 256 * jj) * 16);
      gload16(baseG + off[jj] + kk, lG + (tid + 256 * jj) * 16);
      gload16(baseU + off[jj] + kk, lU + (tid + 256 * jj) * 16);
    }
    // per-group scales (global, L2-resident; issued before barrier)
    f32x4 sx[4];
    float sg[4], su[4];
#pragma unroll
    for (int i = 0; i < 4; ++i)
      sx[i] = *(const f32x4*)(XsT + g * 4096 + m0 + wr + i * 16 + quad * 4);
#pragma unroll
    for (int jj = 0; jj < 4; ++jj) {
      sg[jj] = GsT[g * 16384 + n0 + wc + jj * 16 + l16];
      su[jj] = GsT[g * 16384 + 8192 + n0 + wc + jj * 16 + l16];
    }
    __syncthreads();

    i32x4 a[4][2];
#pragma unroll
    for (int i = 0; i < 4; ++i) {
      a[i][0] = *(const i32x4*)(lA + aoff[0][i]);
      a[i][1] = *(const i32x4*)(lA + aoff[1][i]);
    }
#pragma unroll
    for (int jj = 0; jj < 4; ++jj) {
      i32x4 bg0 = *(const i32x4*)(lG + boff[0][jj]);
      i32x4 bg1 = *(const i32x4*)(lG + boff[1][jj]);
      i32x4 bu0 = *(const i32x4*)(lU + boff[0][jj]);
      i32x4 bu1 = *(const i32x4*)(lU + boff[1][jj]);
#pragma unroll
      for (int i = 0; i < 4; ++i) {
        i32x4 zero = {0, 0, 0, 0};
        i32x4 ig = __builtin_amdgcn_mfma_i32_16x16x64_i8(a[i][0], bg0, zero, 0, 0, 0);
        ig = __builtin_amdgcn_mfma_i32_16x16x64_i8(a[i][1], bg1, ig, 0, 0, 0);
        i32x4 iu = __builtin_amdgcn_mfma_i32_16x16x64_i8(a[i][0], bu0, zero, 0, 0, 0);
        iu = __builtin_amdgcn_mfma_i32_16x16x64_i8(a[i][1], bu1, iu, 0, 0, 0);
#pragma unroll
        for (int r = 0; r < 4; ++r) {
          float sc = sx[i][r];
          fg[i][jj][r] = fmaf((float)ig[r], sc * sg[jj], fg[i][jj][r]);
          fu[i][jj][r] = fmaf((float)iu[r], sc * su[jj], fu[i][jj][r]);
        }
      }
    }
    __syncthreads();
  }

  // ---- epilogue: silu(g)*u, per-row (128-col group) absmax, int8 quantize ----
#pragma unroll
  for (int i = 0; i < 4; ++i)
#pragma unroll
    for (int jj = 0; jj < 4; ++jj)
#pragma unroll
      for (int r = 0; r < 4; ++r) {
        float gv = fg[i][jj][r];
        float uv = fu[i][jj][r];
        fg[i][jj][r] = (gv / (1.f + __expf(-gv))) * uv;
      }

  float rmx[4][4];
#pragma unroll
  for (int i = 0; i < 4; ++i)
#pragma unroll
    for (int r = 0; r < 4; ++r) {
      float m = 0.f;
#pragma unroll
      for (int jj = 0; jj < 4; ++jj) m = fmaxf(m, fabsf(fg[i][jj][r]));
      m = fmaxf(m, __shfl_xor(m, 1));
      m = fmaxf(m, __shfl_xor(m, 2));
      m = fmaxf(m, __shfl_xor(m, 4));
      m = fmaxf(m, __shfl_xor(m, 8));
      rmx[i][r] = m;
    }
  if (l16 == 0) {
#pragma unroll
    for (int i = 0; i < 4; ++i)
#pragma unroll
      for (int r = 0; r < 4; ++r)
        rmax[wcI][wr + i * 16 + quad * 4 + r] = rmx[i][r];
  }
  __syncthreads();

#pragma unroll
  for (int i = 0; i < 4; ++i)
#pragma unroll
    for (int r = 0; r < 4; ++r) {
      int mrow = wr + i * 16 + quad * 4 + r;
      float mx = fmaxf(rmax[0][mrow], rmax[1][mrow]);
      float inv = mx > 0.f ? 127.f / mx : 0.f;
#pragma unroll
      for (int jj = 0; jj < 4; ++jj) {
        int q = (int)rintf(fg[i][jj][r] * inv);
        lA[mrow * 128 + wc + jj * 16 + l16] = (signed char)q;
      }
    }
  if (tid < 128) {
    float mx = fmaxf(rmax[0][tid], rmax[1][tid]);
    AsT[(n0 >> 7) * 4096 + m0 + tid] = mx * (1.f / 127.f);
  }
  __syncthreads();

#pragma unroll
  for (int t = 0; t < 4; ++t) {
    int c = tid + 256 * t;
    int row = c >> 3;
    int col = (c & 7) * 16;
    *(int4*)(act + (size_t)(m0 + row) * 8192 + n0 + col) = *(const int4*)(lA + row * 128 + col);
  }
}

// ---------------- GEMM2: out = dequant(act)@Wd^T + bias ----------------
__global__ __launch_bounds__(256, 2) void gemm_down_i8(
    const signed char* __restrict__ Aq, const signed char* __restrict__ Wq,
    const float* __restrict__ AsT,   // [64][4096]
    const float* __restrict__ DsT,   // [64][3072]
    const float* __restrict__ bias,
    float* __restrict__ out) {
  const int K = 8192;
  const int bid = blockIdx.x;
  const int xcd = bid & 7;
  const int jb  = bid >> 3;
  const int jn  = jb % 12;
  const int jm  = jb / 12;
  const int n0  = (12 * (xcd & 1) + jn) * 128;
  const int m0  = (8 * (xcd >> 1) + jm) * 128;
  __shared__ signed char lA[16384];
  __shared__ signed char lB[16384];

  const int tid  = threadIdx.x;
  const int l    = tid & 63;
  const int quad = l >> 4;
  const int l16  = l & 15;
  const int wr   = ((tid >> 6) >> 1) * 64;
  const int wc   = ((tid >> 6) & 1) * 64;

  f32x4 fc[4][4] = {};

  int off[4];
#pragma unroll
  for (int jj = 0; jj < 4; ++jj) {
    int c   = tid + 256 * jj;
    int row = c >> 3;
    int log = (c & 7) ^ (row & 7);
    off[jj] = row * K + log * 16;
  }
  const signed char* baseA = Aq + (size_t)m0 * K;
  const signed char* baseB = Wq + (size_t)n0 * K;

  int aoff[2][4], boff[2][4];
#pragma unroll
  for (int h = 0; h < 2; ++h) {
    int slot = h * 4 + quad;
#pragma unroll
    for (int i = 0; i < 4; ++i) {
      int ra = wr + i * 16 + l16;
      aoff[h][i] = ra * 128 + ((slot ^ (ra & 7)) * 16);
      int rb = wc + i * 16 + l16;
      boff[h][i] = rb * 128 + ((slot ^ (rb & 7)) * 16);
    }
  }

  for (int g = 0; g < 64; ++g) {
    const int kk = g << 7;
#pragma unroll
    for (int jj = 0; jj < 4; ++jj) {
      gload16(baseA + off[jj] + kk, lA + (tid + 256 * jj) * 16);
      gload16(baseB + off[jj] + kk, lB + (tid + 256 * jj) * 16);
    }
    f32x4 sx[4];
    float sn[4];
#pragma unroll
    for (int i = 0; i < 4; ++i)
      sx[i] = *(const f32x4*)(AsT + g * 4096 + m0 + wr + i * 16 + quad * 4);
#pragma unroll
    for (int jj = 0; jj < 4; ++jj)
      sn[jj] = DsT[g * 3072 + n0 + wc + jj * 16 + l16];
    __syncthreads();

    i32x4 a[4][2];
#pragma unroll
    for (int i = 0; i < 4; ++i) {
      a[i][0] = *(const i32x4*)(lA + aoff[0][i]);
      a[i][1] = *(const i32x4*)(lA + aoff[1][i]);
    }
#pragma unroll
    for (int jj = 0; jj < 4; ++jj) {
      i32x4 b0 = *(const i32x4*)(lB + boff[0][jj]);
      i32x4 b1 = *(const i32x4*)(lB + boff[1][jj]);
#pragma unroll
      for (int i = 0; i < 4; ++i) {
        i32x4 zero = {0, 0, 0, 0};
        i32x4 ic = __builtin_amdgcn_mfma_i32_16x16x64_i8(a[i][0], b0, zero, 0, 0, 0);
        ic = __builtin_amdgcn_mfma_i32_16x16x64_i8(a[i][1], b1, ic, 0, 0, 0);
#pragma unroll
        for (int r = 0; r < 4; ++r)
          fc[i][jj][r] = fmaf((float)ic[r], sx[i][r] * sn[jj], fc[i][jj][r]);
      }
    }
    __syncthreads();
  }

  float bj[4];
#pragma unroll
  for (int jj = 0; jj < 4; ++jj) bj[jj] = bias[n0 + wc + jj * 16 + l16];

#pragma unroll
  for (int i = 0; i < 4; ++i)
#pragma unroll
    for (int jj = 0; jj < 4; ++jj)
#pragma unroll
      for (int r = 0; r < 4; ++r) {
        int m = m0 + wr + i * 16 + quad * 4 + r;
        int n = n0 + wc + jj * 16 + l16;
        out[(size_t)m * 3072 + n] = fc[i][jj][r] + bj[jj];
      }
}

extern "C" void kernel_launch(void* const* d_in, const int* in_sizes, int n_in,
                              void* d_out, int out_size, void* d_ws, size_t ws_size,
                              hipStream_t stream) {
  const float* x        = (const float*)d_in[0];
  const int*   gup_qw   = (const int*)d_in[1];
  const int*   gup_qz   = (const int*)d_in[2];
  const float* gup_sc   = (const float*)d_in[3];
  const int*   down_qw  = (const int*)d_in[4];
  const int*   down_qz  = (const int*)d_in[5];
  const float* down_sc  = (const float*)d_in[6];
  const float* down_b   = (const float*)d_in[7];
  float* out = (float*)d_out;

  char* ws = (char*)d_ws;
  signed char* Xq    = (signed char*)(ws);                 // 12,582,912
  signed char* Wgupq = (signed char*)(ws + 12582912);      // 50,331,648
  signed char* Wdnq  = (signed char*)(ws + 62914560);      // 25,165,824
  signed char* Actq  = (signed char*)(ws + 88080384);      // 33,554,432
  float* XsT = (float*)(ws + 121634816);                   // 24x4096
  float* GsT = (float*)(ws + 122028032);                   // 24x16384
  float* DsT = (float*)(ws + 123600896);                   // 64x3072
  float* AsT = (float*)(ws + 124387328);                   // 64x4096

  quant_x<<<24576, 256, 0, stream>>>(x, Xq, XsT);
  requant_k<3072><<<24576, 256, 0, stream>>>(gup_qw, gup_qz, Wgupq);
  requant_k<8192><<<12288, 256, 0, stream>>>(down_qw, down_qz, Wdnq);
  transpose_sc<<<1536, 256, 0, stream>>>(gup_sc, GsT, 16384, 24);
  transpose_sc<<<768, 256, 0, stream>>>(down_sc, DsT, 3072, 64);
  gemm_gateup_i8<<<2048, 256, 0, stream>>>(Xq, Wgupq, XsT, GsT, Actq, AsT);
  gemm_down_i8<<<768, 256, 0, stream>>>(Actq, Wdnq, AsT, DsT, down_b, out);
}

// Round 5
// 806.924 us; speedup vs baseline: 1.3021x; 1.0377x over previous
//
#include <hip/hip_runtime.h>

// Phi3 quantized MLP on MI355X (gfx950) — R5: quad-shared A-scales + packed-f32 rescale.
// R4 post-mortem: per-group f32 rescale is VALU-bound (46% VALUBusy, ~370 us chip-wide:
// 2.4e9 elems x (cvt + mul + fma)). Fix: x/act int8 scales shared across row-QUADS of 4
// (matches MFMA C-layout r-dim) -> scale product sxq[i]*sg[jj] hoists out of the r loop;
// accumulate via float2 elementwise fma -> v_pk_fma_f32. Weights stay exact per-group int8.

typedef float f32x4 __attribute__((ext_vector_type(4)));
typedef float f32x2 __attribute__((ext_vector_type(2)));
typedef int   i32x4 __attribute__((ext_vector_type(4)));

__device__ __forceinline__ void gload16(const void* g, void* l) {
  __builtin_amdgcn_global_load_lds(
      (const __attribute__((address_space(1))) void*)g,
      (__attribute__((address_space(3))) void*)l, 16, 0, 0);
}

// ---------------- quantize x: f32 -> int8, scale per (row-quad of 4, group of 128) ----------------
// grid (24, 1024): g = blockIdx.x, row-quad = blockIdx.y. Xs4: [24][1024]
__global__ __launch_bounds__(256) void quant_x(const float* __restrict__ x,
                                               signed char* __restrict__ Xq,
                                               float* __restrict__ Xs4) {
  int g    = blockIdx.x;
  int rq   = blockIdx.y;
  int w    = threadIdx.x >> 6;
  int lane = threadIdx.x & 63;
  int row  = rq * 4 + w;
  __shared__ float wmax[4];
  const float2 v = *(const float2*)(x + (size_t)row * 3072 + g * 128 + lane * 2);
  float m = fmaxf(fabsf(v.x), fabsf(v.y));
#pragma unroll
  for (int s = 1; s < 64; s <<= 1) m = fmaxf(m, __shfl_xor(m, s));
  if (lane == 0) wmax[w] = m;
  __syncthreads();
  float m4 = fmaxf(fmaxf(wmax[0], wmax[1]), fmaxf(wmax[2], wmax[3]));
  float inv = m4 > 0.f ? 127.f / m4 : 0.f;
  int qa = (int)rintf(v.x * inv);
  int qb = (int)rintf(v.y * inv);
  unsigned short pk = (unsigned short)((qa & 0xff) | ((qb & 0xff) << 8));
  *(unsigned short*)(Xq + (size_t)row * 3072 + g * 128 + lane * 2) = pk;
  if (threadIdx.x == 0) Xs4[g * 1024 + rq] = m4 * (1.f / 127.f);
}

// ---------------- requant weights: int32 q,z -> int8 (q - z), exact ----------------
template <int K>
__global__ __launch_bounds__(256) void requant_k(const int* __restrict__ qw,
                                                 const int* __restrict__ qz,
                                                 signed char* __restrict__ W) {
  constexpr int KG = K / 128;
  constexpr int perrow = K / 8;
  int idx = blockIdx.x * 256 + threadIdx.x;
  int row = idx / perrow;
  int c8  = idx - row * perrow;
  int k   = c8 << 3;
  int z   = qz[row * KG + (k >> 7)];
  const int4* q4 = (const int4*)(qw + (size_t)row * K + k);
  int4 qa = q4[0];
  int4 qb = q4[1];
  int b0 = ((qa.x - z) & 0xff) | (((qa.y - z) & 0xff) << 8) |
           (((qa.z - z) & 0xff) << 16) | (((qa.w - z) & 0xff) << 24);
  int b1 = ((qb.x - z) & 0xff) | (((qb.y - z) & 0xff) << 8) |
           (((qb.z - z) & 0xff) << 16) | (((qb.w - z) & 0xff) << 24);
  int2 o; o.x = b0; o.y = b1;
  *(int2*)(W + (size_t)row * K + k) = o;
}

// ---------------- scale transpose: [R][G] -> [G][R] ----------------
__global__ __launch_bounds__(256) void transpose_sc(const float* __restrict__ in,
                                                    float* __restrict__ out,
                                                    int R, int G) {
  int idx = blockIdx.x * 256 + threadIdx.x;
  int r = idx / G;
  int g = idx - r * G;
  out[(size_t)g * R + r] = in[idx];
}

// LDS tile: 128 rows x 128 bytes, XOR-swizzled (phys chunk p holds logical p^(row&7)).

// ---------------- GEMM1: act = silu(x@Wg^T)*(x@Wu^T), int8 in, int8 out ----------------
__global__ __launch_bounds__(256, 2) void gemm_gateup_i8(
    const signed char* __restrict__ Xq, const signed char* __restrict__ Wq,
    const float* __restrict__ Xs4,   // [24][1024]
    const float* __restrict__ GsT,   // [24][16384]
    signed char* __restrict__ act,   // [4096][8192]
    float* __restrict__ As4) {       // [64][1024]
  const int K = 3072;
  const int bid = blockIdx.x;
  const int xcd = bid & 7;
  const int jb  = bid >> 3;
  const int n0  = ((xcd << 3) + (jb & 7)) * 128;
  const int m0  = (jb >> 3) * 128;
  __shared__ signed char lA[16384];
  __shared__ signed char lG[16384];
  __shared__ signed char lU[16384];
  __shared__ float rmax[2][128];
  __shared__ float rmax4[32];

  const int tid  = threadIdx.x;
  const int l    = tid & 63;
  const int quad = l >> 4;
  const int l16  = l & 15;
  const int wcI  = (tid >> 6) & 1;
  const int wr   = ((tid >> 6) >> 1) * 64;
  const int wc   = wcI * 64;

  f32x2 fg[4][4][2] = {};
  f32x2 fu[4][4][2] = {};

  int off[4];
#pragma unroll
  for (int jj = 0; jj < 4; ++jj) {
    int c   = tid + 256 * jj;
    int row = c >> 3;
    int log = (c & 7) ^ (row & 7);
    off[jj] = row * K + log * 16;
  }
  const signed char* baseA = Xq + (size_t)m0 * K;
  const signed char* baseG = Wq + (size_t)n0 * K;
  const signed char* baseU = Wq + (size_t)(8192 + n0) * K;

  int aoff[2][4], boff[2][4];
#pragma unroll
  for (int h = 0; h < 2; ++h) {
    int slot = h * 4 + quad;
#pragma unroll
    for (int i = 0; i < 4; ++i) {
      int ra = wr + i * 16 + l16;
      aoff[h][i] = ra * 128 + ((slot ^ (ra & 7)) * 16);
      int rb = wc + i * 16 + l16;
      boff[h][i] = rb * 128 + ((slot ^ (rb & 7)) * 16);
    }
  }
  const int qbase = (m0 >> 2) + (wr >> 2) + quad;   // row-quad index base (i adds i*4)

  for (int g = 0; g < 24; ++g) {
    const int kk = g << 7;
#pragma unroll
    for (int jj = 0; jj < 4; ++jj) {
      gload16(baseA + off[jj] + kk, lA + (tid + 256 * jj) * 16);
      gload16(baseG + off[jj] + kk, lG + (tid + 256 * jj) * 16);
      gload16(baseU + off[jj] + kk, lU + (tid + 256 * jj) * 16);
    }
    float sxq[4], sg[4], su[4];
#pragma unroll
    for (int i = 0; i < 4; ++i) sxq[i] = Xs4[g * 1024 + qbase + i * 4];
#pragma unroll
    for (int jj = 0; jj < 4; ++jj) {
      sg[jj] = GsT[g * 16384 + n0 + wc + jj * 16 + l16];
      su[jj] = GsT[g * 16384 + 8192 + n0 + wc + jj * 16 + l16];
    }
    __syncthreads();

    i32x4 a[4][2];
#pragma unroll
    for (int i = 0; i < 4; ++i) {
      a[i][0] = *(const i32x4*)(lA + aoff[0][i]);
      a[i][1] = *(const i32x4*)(lA + aoff[1][i]);
    }
#pragma unroll
    for (int jj = 0; jj < 4; ++jj) {
      i32x4 bg0 = *(const i32x4*)(lG + boff[0][jj]);
      i32x4 bg1 = *(const i32x4*)(lG + boff[1][jj]);
      i32x4 bu0 = *(const i32x4*)(lU + boff[0][jj]);
      i32x4 bu1 = *(const i32x4*)(lU + boff[1][jj]);
#pragma unroll
      for (int i = 0; i < 4; ++i) {
        i32x4 zero = {0, 0, 0, 0};
        i32x4 ig = __builtin_amdgcn_mfma_i32_16x16x64_i8(a[i][0], bg0, zero, 0, 0, 0);
        ig = __builtin_amdgcn_mfma_i32_16x16x64_i8(a[i][1], bg1, ig, 0, 0, 0);
        i32x4 iu = __builtin_amdgcn_mfma_i32_16x16x64_i8(a[i][0], bu0, zero, 0, 0, 0);
        iu = __builtin_amdgcn_mfma_i32_16x16x64_i8(a[i][1], bu1, iu, 0, 0, 0);
        float pgs = sxq[i] * sg[jj];
        float pus = sxq[i] * su[jj];
        f32x2 pg2 = {pgs, pgs};
        f32x2 pu2 = {pus, pus};
        f32x2 g01 = {(float)ig[0], (float)ig[1]};
        f32x2 g23 = {(float)ig[2], (float)ig[3]};
        f32x2 u01 = {(float)iu[0], (float)iu[1]};
        f32x2 u23 = {(float)iu[2], (float)iu[3]};
        fg[i][jj][0] = __builtin_elementwise_fma(g01, pg2, fg[i][jj][0]);
        fg[i][jj][1] = __builtin_elementwise_fma(g23, pg2, fg[i][jj][1]);
        fu[i][jj][0] = __builtin_elementwise_fma(u01, pu2, fu[i][jj][0]);
        fu[i][jj][1] = __builtin_elementwise_fma(u23, pu2, fu[i][jj][1]);
      }
    }
    __syncthreads();
  }

  // ---- epilogue: silu(g)*u -> quad-shared absmax -> int8 ----
  float av[4][4][4];   // [i][jj][r]
#pragma unroll
  for (int i = 0; i < 4; ++i)
#pragma unroll
    for (int jj = 0; jj < 4; ++jj)
#pragma unroll
      for (int r = 0; r < 4; ++r) {
        float gv = fg[i][jj][r >> 1][r & 1];
        float uv = fu[i][jj][r >> 1][r & 1];
        av[i][jj][r] = (gv / (1.f + __expf(-gv))) * uv;
      }

#pragma unroll
  for (int i = 0; i < 4; ++i)
#pragma unroll
    for (int r = 0; r < 4; ++r) {
      float m = 0.f;
#pragma unroll
      for (int jj = 0; jj < 4; ++jj) m = fmaxf(m, fabsf(av[i][jj][r]));
      m = fmaxf(m, __shfl_xor(m, 1));
      m = fmaxf(m, __shfl_xor(m, 2));
      m = fmaxf(m, __shfl_xor(m, 4));
      m = fmaxf(m, __shfl_xor(m, 8));
      if (l16 == 0) rmax[wcI][wr + i * 16 + quad * 4 + r] = m;
    }
  __syncthreads();
  if (tid < 32) {
    float m = 0.f;
#pragma unroll
    for (int k = 0; k < 4; ++k)
      m = fmaxf(m, fmaxf(rmax[0][tid * 4 + k], rmax[1][tid * 4 + k]));
    rmax4[tid] = m;
    As4[(n0 >> 7) * 1024 + (m0 >> 2) + tid] = m * (1.f / 127.f);
  }
  __syncthreads();

#pragma unroll
  for (int i = 0; i < 4; ++i) {
    float mx = rmax4[(wr >> 2) + i * 4 + quad];
    float inv = mx > 0.f ? 127.f / mx : 0.f;
#pragma unroll
    for (int r = 0; r < 4; ++r) {
      int mrow = wr + i * 16 + quad * 4 + r;
#pragma unroll
      for (int jj = 0; jj < 4; ++jj) {
        int q = (int)rintf(av[i][jj][r] * inv);
        lA[mrow * 128 + wc + jj * 16 + l16] = (signed char)q;
      }
    }
  }
  __syncthreads();

#pragma unroll
  for (int t = 0; t < 4; ++t) {
    int c = tid + 256 * t;
    int row = c >> 3;
    int col = (c & 7) * 16;
    *(int4*)(act + (size_t)(m0 + row) * 8192 + n0 + col) = *(const int4*)(lA + row * 128 + col);
  }
}

// ---------------- GEMM2: out = dequant(act)@Wd^T + bias ----------------
__global__ __launch_bounds__(256, 2) void gemm_down_i8(
    const signed char* __restrict__ Aq, const signed char* __restrict__ Wq,
    const float* __restrict__ As4,   // [64][1024]
    const float* __restrict__ DsT,   // [64][3072]
    const float* __restrict__ bias,
    float* __restrict__ out) {
  const int K = 8192;
  const int bid = blockIdx.x;
  const int xcd = bid & 7;
  const int jb  = bid >> 3;
  const int jn  = jb % 12;
  const int jm  = jb / 12;
  const int n0  = (12 * (xcd & 1) + jn) * 128;
  const int m0  = (8 * (xcd >> 1) + jm) * 128;
  __shared__ signed char lA[16384];
  __shared__ signed char lB[16384];

  const int tid  = threadIdx.x;
  const int l    = tid & 63;
  const int quad = l >> 4;
  const int l16  = l & 15;
  const int wr   = ((tid >> 6) >> 1) * 64;
  const int wc   = ((tid >> 6) & 1) * 64;

  f32x2 fc[4][4][2] = {};

  int off[4];
#pragma unroll
  for (int jj = 0; jj < 4; ++jj) {
    int c   = tid + 256 * jj;
    int row = c >> 3;
    int log = (c & 7) ^ (row & 7);
    off[jj] = row * K + log * 16;
  }
  const signed char* baseA = Aq + (size_t)m0 * K;
  const signed char* baseB = Wq + (size_t)n0 * K;

  int aoff[2][4], boff[2][4];
#pragma unroll
  for (int h = 0; h < 2; ++h) {
    int slot = h * 4 + quad;
#pragma unroll
    for (int i = 0; i < 4; ++i) {
      int ra = wr + i * 16 + l16;
      aoff[h][i] = ra * 128 + ((slot ^ (ra & 7)) * 16);
      int rb = wc + i * 16 + l16;
      boff[h][i] = rb * 128 + ((slot ^ (rb & 7)) * 16);
    }
  }
  const int qbase = (m0 >> 2) + (wr >> 2) + quad;

  for (int g = 0; g < 64; ++g) {
    const int kk = g << 7;
#pragma unroll
    for (int jj = 0; jj < 4; ++jj) {
      gload16(baseA + off[jj] + kk, lA + (tid + 256 * jj) * 16);
      gload16(baseB + off[jj] + kk, lB + (tid + 256 * jj) * 16);
    }
    float sxq[4], sn[4];
#pragma unroll
    for (int i = 0; i < 4; ++i) sxq[i] = As4[g * 1024 + qbase + i * 4];
#pragma unroll
    for (int jj = 0; jj < 4; ++jj)
      sn[jj] = DsT[g * 3072 + n0 + wc + jj * 16 + l16];
    __syncthreads();

    i32x4 a[4][2];
#pragma unroll
    for (int i = 0; i < 4; ++i) {
      a[i][0] = *(const i32x4*)(lA + aoff[0][i]);
      a[i][1] = *(const i32x4*)(lA + aoff[1][i]);
    }
#pragma unroll
    for (int jj = 0; jj < 4; ++jj) {
      i32x4 b0 = *(const i32x4*)(lB + boff[0][jj]);
      i32x4 b1 = *(const i32x4*)(lB + boff[1][jj]);
#pragma unroll
      for (int i = 0; i < 4; ++i) {
        i32x4 zero = {0, 0, 0, 0};
        i32x4 ic = __builtin_amdgcn_mfma_i32_16x16x64_i8(a[i][0], b0, zero, 0, 0, 0);
        ic = __builtin_amdgcn_mfma_i32_16x16x64_i8(a[i][1], b1, ic, 0, 0, 0);
        float ps = sxq[i] * sn[jj];
        f32x2 p2 = {ps, ps};
        f32x2 c01 = {(float)ic[0], (float)ic[1]};
        f32x2 c23 = {(float)ic[2], (float)ic[3]};
        fc[i][jj][0] = __builtin_elementwise_fma(c01, p2, fc[i][jj][0]);
        fc[i][jj][1] = __builtin_elementwise_fma(c23, p2, fc[i][jj][1]);
      }
    }
    __syncthreads();
  }

  float bj[4];
#pragma unroll
  for (int jj = 0; jj < 4; ++jj) bj[jj] = bias[n0 + wc + jj * 16 + l16];

#pragma unroll
  for (int i = 0; i < 4; ++i)
#pragma unroll
    for (int jj = 0; jj < 4; ++jj)
#pragma unroll
      for (int r = 0; r < 4; ++r) {
        int m = m0 + wr + i * 16 + quad * 4 + r;
        int n = n0 + wc + jj * 16 + l16;
        out[(size_t)m * 3072 + n] = fc[i][jj][r >> 1][r & 1] + bj[jj];
      }
}

extern "C" void kernel_launch(void* const* d_in, const int* in_sizes, int n_in,
                              void* d_out, int out_size, void* d_ws, size_t ws_size,
                              hipStream_t stream) {
  const float* x        = (const float*)d_in[0];
  const int*   gup_qw   = (const int*)d_in[1];
  const int*   gup_qz   = (const int*)d_in[2];
  const float* gup_sc   = (const float*)d_in[3];
  const int*   down_qw  = (const int*)d_in[4];
  const int*   down_qz  = (const int*)d_in[5];
  const float* down_sc  = (const float*)d_in[6];
  const float* down_b   = (const float*)d_in[7];
  float* out = (float*)d_out;

  char* ws = (char*)d_ws;
  signed char* Xq    = (signed char*)(ws);                 // 12,582,912
  signed char* Wgupq = (signed char*)(ws + 12582912);      // 50,331,648
  signed char* Wdnq  = (signed char*)(ws + 62914560);      // 25,165,824
  signed char* Actq  = (signed char*)(ws + 88080384);      // 33,554,432
  float* Xs4 = (float*)(ws + 121634816);                   // 24x1024
  float* GsT = (float*)(ws + 121733120);                   // 24x16384
  float* DsT = (float*)(ws + 123305984);                   // 64x3072
  float* As4 = (float*)(ws + 124092416);                   // 64x1024

  quant_x<<<dim3(24, 1024), 256, 0, stream>>>(x, Xq, Xs4);
  requant_k<3072><<<24576, 256, 0, stream>>>(gup_qw, gup_qz, Wgupq);
  requant_k<8192><<<12288, 256, 0, stream>>>(down_qw, down_qz, Wdnq);
  transpose_sc<<<1536, 256, 0, stream>>>(gup_sc, GsT, 16384, 24);
  transpose_sc<<<768, 256, 0, stream>>>(down_sc, DsT, 3072, 64);
  gemm_gateup_i8<<<2048, 256, 0, stream>>>(Xq, Wgupq, Xs4, GsT, Actq, As4);
  gemm_down_i8<<<768, 256, 0, stream>>>(Actq, Wdnq, As4, DsT, down_b, out);
}